// Round 3
// baseline (73530.176 us; speedup 1.0000x reference)
//
#include <hip/hip_runtime.h>
#include <stdint.h>
#include <math.h>

#define NBLK 128
#define NTHR 256
#define Bn 16
#define Tn 2000
#define Cn 128
#define Gn 512
#define Hn 512
#define Vn 256

// ws: first 4096 B = flags (16 groups x 64 u32; group g at g*256 B, 8 used).
// Then doubles per group (stride 3072): H0[0,512) H1[512,1024) PL[1024,3072)
#define WS_DBL_BASE 512
#define GRP_STRIDE  3072

#define OUT_SAMP ((size_t)Bn*Tn*Vn)          // 8,192,000
#define OUT_HF   (OUT_SAMP + (size_t)Bn*Tn)  // 8,224,000

typedef __attribute__((ext_vector_type(2))) double d2_t;

__device__ __forceinline__ unsigned rotl32(unsigned v, int n) {
  return (v << n) | (v >> (32 - n));
}

// JAX threefry2x32, 20 rounds, exact.
__device__ __forceinline__ void threefry2x32(unsigned k0, unsigned k1,
                                             unsigned c0, unsigned c1,
                                             unsigned& o0, unsigned& o1) {
  unsigned ks2 = k0 ^ k1 ^ 0x1BD11BDAu;
  unsigned x0 = c0 + k0;
  unsigned x1 = c1 + k1;
#define TF_R(r) { x0 += x1; x1 = rotl32(x1, r); x1 ^= x0; }
  TF_R(13) TF_R(15) TF_R(26) TF_R(6)
  x0 += k1;  x1 += ks2 + 1u;
  TF_R(17) TF_R(29) TF_R(16) TF_R(24)
  x0 += ks2; x1 += k0 + 2u;
  TF_R(13) TF_R(15) TF_R(26) TF_R(6)
  x0 += k0;  x1 += k1 + 3u;
  TF_R(17) TF_R(29) TF_R(16) TF_R(24)
  x0 += k1;  x1 += ks2 + 4u;
  TF_R(13) TF_R(15) TF_R(26) TF_R(6)
  x0 += ks2; x1 += k0 + 5u;
#undef TF_R
  o0 = x0; o1 = x1;
}

// exact JAX partitionable gumbel for step key (kt0,kt1), flat index f
__device__ __forceinline__ double jax_gumbel(unsigned kt0, unsigned kt1,
                                             unsigned f) {
  unsigned r0, r1;
  threefry2x32(kt0, kt1, 0u, f, r0, r1);
  unsigned bits = r0 ^ r1;
  float uf = __uint_as_float((bits >> 9) | 0x3f800000u) - 1.0f;
  if (uf <= 0.f) uf = 1.17549435e-38f;  // np.finfo(float32).tiny
  return -log(-log((double)uf));
}

// ---- cross-block traffic: system-scope (sc0 sc1) ops — PROVEN semantics. ----
// NOTE: all multi-instruction asm blocks use EARLY-CLOBBER ("=&v") outputs.
// With plain "=v", LLVM may allocate an output on top of an address-pair
// input still needed by a LATER load in the same block -> wild address ->
// GPU memory fault (this was round-2's core dump).
__device__ __forceinline__ void st_d(double* p, double v) {
  asm volatile("global_store_dwordx2 %0, %1, off sc0 sc1"
               :: "v"(p), "v"(v) : "memory");
}
__device__ __forceinline__ void ld8(const double* pl, int v, double* o) {
  const double* a0 = pl + v;
  const double* a1 = pl + 512 + v;
  const double* a2 = pl + 1024 + v;
  const double* a3 = pl + 1536 + v;
  double o0, o1, o2, o3, o4, o5, o6, o7;
  asm volatile(
    "global_load_dwordx2 %[r0], %[p0], off sc0 sc1\n\t"
    "global_load_dwordx2 %[r1], %[p0], off offset:2048 sc0 sc1\n\t"
    "global_load_dwordx2 %[r2], %[p1], off sc0 sc1\n\t"
    "global_load_dwordx2 %[r3], %[p1], off offset:2048 sc0 sc1\n\t"
    "global_load_dwordx2 %[r4], %[p2], off sc0 sc1\n\t"
    "global_load_dwordx2 %[r5], %[p2], off offset:2048 sc0 sc1\n\t"
    "global_load_dwordx2 %[r6], %[p3], off sc0 sc1\n\t"
    "global_load_dwordx2 %[r7], %[p3], off offset:2048 sc0 sc1\n\t"
    "s_waitcnt vmcnt(0)"
    : [r0]"=&v"(o0), [r1]"=&v"(o1), [r2]"=&v"(o2), [r3]"=&v"(o3),
      [r4]"=&v"(o4), [r5]"=&v"(o5), [r6]"=&v"(o6), [r7]"=&v"(o7)
    : [p0]"v"(a0), [p1]"v"(a1), [p2]"v"(a2), [p3]"v"(a3));
  o[0]=o0; o[1]=o1; o[2]=o2; o[3]=o3; o[4]=o4; o[5]=o5; o[6]=o6; o[7]=o7;
}
// h reload: lane's k-slice h[8l..8l+7] + this lane's row element h[row]
__device__ __forceinline__ void ldh(const double* hb, int lane, int row,
                                    double* hc, double& hold) {
  const double* cp = hb + 8 * lane;
  const double* rp = hb + row;
  d2_t c0, c1, c2, c3; double hv;
  asm volatile(
    "global_load_dwordx4 %[a], %[p], off sc0 sc1\n\t"
    "global_load_dwordx4 %[b], %[p], off offset:16 sc0 sc1\n\t"
    "global_load_dwordx4 %[c], %[p], off offset:32 sc0 sc1\n\t"
    "global_load_dwordx4 %[d], %[p], off offset:48 sc0 sc1\n\t"
    "global_load_dwordx2 %[h], %[q], off sc0 sc1\n\t"
    "s_waitcnt vmcnt(0)"
    : [a]"=&v"(c0), [b]"=&v"(c1), [c]"=&v"(c2), [d]"=&v"(c3), [h]"=&v"(hv)
    : [p]"v"(cp), [q]"v"(rp));
  hc[0]=c0.x; hc[1]=c0.y; hc[2]=c1.x; hc[3]=c1.y;
  hc[4]=c2.x; hc[5]=c2.y; hc[6]=c3.x; hc[7]=c3.y; hold = hv;
}
__device__ __forceinline__ unsigned ld_u(const unsigned* p) {
  unsigned r;
  asm volatile("global_load_dword %0, %1, off sc0 sc1\n\t"
               "s_waitcnt vmcnt(0)" : "=&v"(r) : "v"(p) : "memory");
  return r;
}
__device__ __forceinline__ void st_u(unsigned* p, unsigned v) {
  asm volatile("global_store_dword %0, %1, off sc0 sc1"
               :: "v"(p), "v"(v) : "memory");
}

// split 8-way group barrier: arrive (drain stores + flag), then wait (spin).
__device__ __forceinline__ void gar(unsigned* flags, int slot, unsigned target) {
  asm volatile("s_waitcnt vmcnt(0)" ::: "memory");
  __syncthreads();
  if (threadIdx.x == 0) st_u(&flags[slot], target);
}
__device__ __forceinline__ void gwt(unsigned* flags, unsigned target) {
  if (threadIdx.x < 8) {
    int guard = 0;
    while (ld_u(&flags[threadIdx.x]) < target) {
      if (++guard > 5000000) break;  // safety: never hang the bench
    }
  }
  asm volatile("" ::: "memory");
  __syncthreads();
}

// Butterfly transpose-reduce: in p[i] = this lane's k-partial of row base+i.
// Returns full 64-lane sum of row base+(lane&7), replicated per 8-lane group.
__device__ __forceinline__ double reduce8(const double* p, int lane) {
  double q[4];
#pragma unroll
  for (int m = 0; m < 4; ++m) {
    double a = p[2*m], b = p[2*m+1];
    double t = (lane & 1) ? a : b;
    double u = __shfl_xor(t, 1, 64);
    q[m] = ((lane & 1) ? b : a) + u;
  }
  double r[2];
#pragma unroll
  for (int m = 0; m < 2; ++m) {
    double a = q[2*m], b = q[2*m+1];
    double t = (lane & 2) ? a : b;
    double u = __shfl_xor(t, 2, 64);
    r[m] = ((lane & 2) ? b : a) + u;
  }
  double a = r[0], b = r[1];
  double t = (lane & 4) ? a : b;
  double u = __shfl_xor(t, 4, 64);
  double f = ((lane & 4) ? b : a) + u;
  f += __shfl_xor(f, 8, 64);
  f += __shfl_xor(f, 16, 64);
  f += __shfl_xor(f, 32, 64);
  return f;
}

extern "C" __global__ __launch_bounds__(NTHR, 1)
void wavernn_pipe(const float* __restrict__ cond, const float* __restrict__ h0,
                  const float* __restrict__ W_ih, const float* __restrict__ W_hh,
                  const float* __restrict__ b_ih, const float* __restrict__ b_hh,
                  const float* __restrict__ W_hid, const float* __restrict__ b_hid,
                  const float* __restrict__ W_out, const float* __restrict__ b_out,
                  const float* __restrict__ emb,
                  float* __restrict__ out, double* __restrict__ ws) {
  const int tid = threadIdx.x;
  const int blk = blockIdx.x;
  const int g = blk >> 3;   // batch element (group)
  const int j = blk & 7;    // slot; slot-major => weight slice j is XCD-local
  const int lane = tid & 63, wv = tid >> 6;
  const int grp8 = lane >> 3;   // 8-lane group id, used for owner writes

  unsigned* flags = ((unsigned*)ws) + (size_t)g * 64;
  double* G   = ws + WS_DBL_BASE + (size_t)g * GRP_STRIDE;
  double* Hb0 = G;
  double* Hb1 = G + 512;
  double* PL  = G + 1024;   // 8 x 256 partial logits

  __shared__ __attribute__((aligned(32))) double s_x[Cn];
  __shared__ double s_hg[3][64];     // h-dot sums (r,z,n) for this block's rows
  __shared__ double s_xg[3][64];     // x-dot sums
  __shared__ double s_hidraw[64];
  __shared__ __attribute__((aligned(32))) double s_hid[64];
  __shared__ double s_gum[256];
  __shared__ float  s_cond[Cn];
  __shared__ double s_pv[4];
  __shared__ int    s_pi[4];

  // ---- per-thread constants (biases are t-invariant) ----
  const int rrow = j * 64 + lane;
  double bih_r = 0., bih_z = 0., bih_n = 0.;
  double bhh_r = 0., bhh_z = 0., bhh_n = 0., bhid = 0.;
  if (wv == 0) {
    bih_r = (double)b_ih[rrow]; bih_z = (double)b_ih[512 + rrow];
    bih_n = (double)b_ih[1024 + rrow];
    bhh_r = (double)b_hh[rrow]; bhh_z = (double)b_hh[512 + rrow];
    bhh_n = (double)b_hh[1024 + rrow];
    bhid  = (double)b_hid[rrow];
  }
  const double bout_reg = (double)b_out[tid];

  double hc[8];      // this lane's k-slice of h: h[8*lane .. 8*lane+7]
  double hold = 0.;  // h[j*64+lane] (old h for the z-blend, wave 0 uses it)

  // ---- init: H0 slice <- h0; x0 = cond[:,0,:] + emb[128] ----
  if (tid < 64) st_d(&Hb0[j * 64 + tid],
                     (double)h0[(size_t)g * Gn + j * 64 + tid]);
  if (tid < Cn) s_x[tid] = (double)cond[(size_t)g * Tn * Cn + tid]
                         + (double)emb[128 * Cn + tid];
  gar(flags, j, 1u); gwt(flags, 1u);
  ldh(Hb0, lane, rrow, hc, hold);   // h_0 into registers

  for (int t = 0; t < Tn; ++t) {
    double* hnxt = (t & 1) ? Hb0 : Hb1;       // buffer for h_{t+1}

    // ===== WINDOW (overlaps in-flight PL_{t-1} round trip) =====
    // waves 0-2: W_hh k-parallel dots (coalesced), gate = wv
    if (wv <= 2) {
      const float* Wrow = W_hh + (size_t)(wv * 512 + j * 64) * Gn;
      const float* lptr = Wrow + 8 * lane;
#pragma unroll
      for (int b = 0; b < 8; ++b) {
        double p[8];
#pragma unroll
        for (int i = 0; i < 8; ++i) {
          const float4 wlo = *(const float4*)(lptr + (size_t)i * Gn);
          const float4 whi = *(const float4*)(lptr + (size_t)i * Gn + 4);
          double s = 0.;
          s = fma((double)wlo.x, hc[0], s); s = fma((double)wlo.y, hc[1], s);
          s = fma((double)wlo.z, hc[2], s); s = fma((double)wlo.w, hc[3], s);
          s = fma((double)whi.x, hc[4], s); s = fma((double)whi.y, hc[5], s);
          s = fma((double)whi.z, hc[6], s); s = fma((double)whi.w, hc[7], s);
          p[i] = s;
        }
        double f = reduce8(p, lane);
        if (grp8 == b) s_hg[wv][lane] = f;
        lptr += 8 * Gn;
      }
    } else {
      // wave 3: stage cond[:,t,:] ; gumbel for step t-1 (consumed at resolve)
      const int c0 = 2 * lane;
      s_cond[c0]     = cond[((size_t)g * Tn + t) * Cn + c0];
      s_cond[c0 + 1] = cond[((size_t)g * Tn + t) * Cn + c0 + 1];
      if (t > 0) {
        unsigned kt0, kt1;
        threefry2x32(0u, 1u, 0u, (unsigned)(t - 1), kt0, kt1);
#pragma unroll
        for (int i = 0; i < 4; ++i) {
          int v = 4 * lane + i;
          s_gum[v] = jax_gumbel(kt0, kt1, (unsigned)(g * Vn + v));
        }
      }
    }

    // ===== PL wait + resolve of step t-1 =====
    if (t > 0) {
      gwt(flags, (unsigned)(2 * t + 1));   // PL_{t-1} ready (gar'd 2(t-1)+3)
      const int v = tid;
      double l[8];
      ld8(PL, v, l);
      double logit = ((((((((l[0] + l[1]) + l[2]) + l[3]) + l[4]) + l[5])
                       + l[6]) + l[7])) + bout_reg;
      if (j == 0)
        out[(size_t)g * Tn * Vn + (size_t)(t - 1) * Vn + v] = (float)logit;
      double bv = logit + s_gum[v];
      int bi = v;
#pragma unroll
      for (int off = 1; off < 64; off <<= 1) {
        double ov = __shfl_xor(bv, off, 64);
        int oi = __shfl_xor(bi, off, 64);
        if (ov > bv || (ov == bv && oi < bi)) { bv = ov; bi = oi; }
      }
      if (lane == 0) { s_pv[wv] = bv; s_pi[wv] = bi; }
      __syncthreads();
      double fv = s_pv[0]; int fi = s_pi[0];
#pragma unroll
      for (int w = 1; w < 4; ++w) {
        double ov = s_pv[w]; int oi = s_pi[w];
        if (ov > fv || (ov == fv && oi < fi)) { fv = ov; fi = oi; }
      }
      const int samp = fi;
      if (tid == 0 && j == 0)
        out[OUT_SAMP + (size_t)g * Tn + (t - 1)] = (float)samp;
      if (tid < Cn)
        s_x[tid] = (double)s_cond[tid] + (double)emb[(size_t)samp * Cn + tid];
      __syncthreads();
    } else {
      __syncthreads();  // order window LDS writes vs x-phase reads
    }

    // ===== x-phase: W_ih k-parallel dots (waves 0,1,3) =====
    if (wv != 2) {
      const int gi_ = (wv == 3) ? 2 : wv;
      const double x0 = s_x[2 * lane], x1 = s_x[2 * lane + 1];
      const float* Wrow = W_ih + (size_t)(gi_ * 512 + j * 64) * Cn;
      const float* lptr = Wrow + 2 * lane;
#pragma unroll
      for (int b = 0; b < 8; ++b) {
        double p[8];
#pragma unroll
        for (int i = 0; i < 8; ++i) {
          const float2 w = *(const float2*)(lptr + (size_t)i * Cn);
          p[i] = fma((double)w.x, x0, (double)w.y * x1);
        }
        double f = reduce8(p, lane);
        if (grp8 == b) s_xg[gi_][lane] = f;
        lptr += 8 * Cn;
      }
    }
    __syncthreads();

    // ===== combine (wave 0) -> h_{t+1} slice =====
    if (wv == 0) {
      double hr = s_hg[0][lane] + bhh_r;
      double hz = s_hg[1][lane] + bhh_z;
      double hn = s_hg[2][lane] + bhh_n;
      double xr = s_xg[0][lane] + bih_r;
      double xz = s_xg[1][lane] + bih_z;
      double xn = s_xg[2][lane] + bih_n;
      double r = 1.0 / (1.0 + exp(-(xr + hr)));
      double z = 1.0 / (1.0 + exp(-(xz + hz)));
      double n = tanh(xn + r * hn);
      double hv = (1.0 - z) * n + z * hold;
      st_d(&hnxt[j * 64 + lane], hv);
    }
    gar(flags, j, (unsigned)(2 * t + 2));
    gwt(flags, (unsigned)(2 * t + 2));
    ldh(hnxt, lane, rrow, hc, hold);          // h_{t+1} into registers
    if (t == Tn - 1 && j == 0 && wv == 0) {
#pragma unroll
      for (int i = 0; i < 8; ++i)
        out[OUT_HF + (size_t)g * Gn + 8 * lane + i] = (float)hc[i];
    }

    // ===== B: hid slice (k-parallel) + partial logits =====
    {
      const float* Wrow = W_hid + (size_t)(j * 64 + wv * 16) * Gn;
      const float* lptr = Wrow + 8 * lane;
#pragma unroll
      for (int b = 0; b < 2; ++b) {
        double p[8];
#pragma unroll
        for (int i = 0; i < 8; ++i) {
          const float4 wlo = *(const float4*)(lptr + (size_t)i * Gn);
          const float4 whi = *(const float4*)(lptr + (size_t)i * Gn + 4);
          double s = 0.;
          s = fma((double)wlo.x, hc[0], s); s = fma((double)wlo.y, hc[1], s);
          s = fma((double)wlo.z, hc[2], s); s = fma((double)wlo.w, hc[3], s);
          s = fma((double)whi.x, hc[4], s); s = fma((double)whi.y, hc[5], s);
          s = fma((double)whi.z, hc[6], s); s = fma((double)whi.w, hc[7], s);
          p[i] = s;
        }
        double f = reduce8(p, lane);
        if (grp8 == 2 * wv + b) s_hidraw[lane] = f;
        lptr += 8 * Gn;
      }
    }
    __syncthreads();
    if (tid < 64) {
      double acc = s_hidraw[tid] + bhid;
      s_hid[tid] = acc > 0.0 ? acc : 0.0;
    }
    __syncthreads();
    {
      const double hidl = s_hid[lane];
      const float* lptr = W_out + (size_t)(wv * 64) * Hn + j * 64 + lane;
#pragma unroll
      for (int b = 0; b < 8; ++b) {
        double p[8];
#pragma unroll
        for (int i = 0; i < 8; ++i)
          p[i] = (double)lptr[(size_t)i * Hn] * hidl;
        double f = reduce8(p, lane);
        if (grp8 == b) st_d(&PL[j * 256 + wv * 64 + lane], f);
        lptr += (size_t)8 * Hn;
      }
    }
    gar(flags, j, (unsigned)(2 * t + 3));
  }

  // ===== final resolve: step Tn-1 =====
  gwt(flags, (unsigned)(2 * Tn + 1));
  {
    const int v = tid;
    double l[8];
    ld8(PL, v, l);
    double logit = ((((((((l[0] + l[1]) + l[2]) + l[3]) + l[4]) + l[5])
                     + l[6]) + l[7])) + bout_reg;
    if (j == 0)
      out[(size_t)g * Tn * Vn + (size_t)(Tn - 1) * Vn + v] = (float)logit;
    unsigned kt0, kt1;
    threefry2x32(0u, 1u, 0u, (unsigned)(Tn - 1), kt0, kt1);
    double gum = jax_gumbel(kt0, kt1, (unsigned)(g * Vn + v));
    double bv = logit + gum;
    int bi = v;
#pragma unroll
    for (int off = 1; off < 64; off <<= 1) {
      double ov = __shfl_xor(bv, off, 64);
      int oi = __shfl_xor(bi, off, 64);
      if (ov > bv || (ov == bv && oi < bi)) { bv = ov; bi = oi; }
    }
    if (lane == 0) { s_pv[wv] = bv; s_pi[wv] = bi; }
    __syncthreads();
    double fv = s_pv[0]; int fi = s_pi[0];
#pragma unroll
    for (int w = 1; w < 4; ++w) {
      double ov = s_pv[w]; int oi = s_pi[w];
      if (ov > fv || (ov == fv && oi < fi)) { fv = ov; fi = oi; }
    }
    if (tid == 0 && j == 0)
      out[OUT_SAMP + (size_t)g * Tn + (Tn - 1)] = (float)fi;
  }
}

extern "C" void kernel_launch(void* const* d_in, const int* in_sizes, int n_in,
                              void* d_out, int out_size, void* d_ws, size_t ws_size,
                              hipStream_t stream) {
  const float* cond  = (const float*)d_in[0];
  const float* h0    = (const float*)d_in[1];
  const float* W_ih  = (const float*)d_in[2];
  const float* W_hh  = (const float*)d_in[3];
  const float* b_ih  = (const float*)d_in[4];
  const float* b_hh  = (const float*)d_in[5];
  const float* W_hid = (const float*)d_in[6];
  const float* b_hid = (const float*)d_in[7];
  const float* W_out = (const float*)d_in[8];
  const float* b_out = (const float*)d_in[9];
  const float* emb   = (const float*)d_in[10];

  // zero the flag region (ws is poisoned 0xAA before every call)
  hipMemsetAsync(d_ws, 0, 4096, stream);
  hipLaunchKernelGGL(wavernn_pipe, dim3(NBLK), dim3(NTHR), 0, stream,
                     cond, h0, W_ih, W_hh, b_ih, b_hh, W_hid, b_hid,
                     W_out, b_out, emb, (float*)d_out, (double*)d_ws);
}

// Round 5
// 48824.545 us; speedup vs baseline: 1.5060x; 1.5060x over previous
//
#include <hip/hip_runtime.h>
#include <stdint.h>
#include <math.h>

#define NBLK 128
#define NTHR 256
#define Bn 16
#define Tn 2000
#define Cn 128
#define Gn 512
#define Hn 512
#define Vn 256

// ws: first 4096 B = per-group sync (16 groups x 64 u32; group g at g*256 B):
//   u32[0]  = ctrH : monotonic arrival counter, h-exchange barriers
//   u32[32] = ctrP : monotonic arrival counter, PL-ready barriers (128B apart)
// Then doubles per group (stride 3072): H0[0,512) H1[512,1024) PL[1024,3072)
#define WS_DBL_BASE 512
#define GRP_STRIDE  3072

#define OUT_SAMP ((size_t)Bn*Tn*Vn)          // 8,192,000
#define OUT_HF   (OUT_SAMP + (size_t)Bn*Tn)  // 8,224,000

typedef __attribute__((ext_vector_type(2))) double d2_t;

__device__ __forceinline__ unsigned rotl32(unsigned v, int n) {
  return (v << n) | (v >> (32 - n));
}

// JAX threefry2x32, 20 rounds, exact.
__device__ __forceinline__ void threefry2x32(unsigned k0, unsigned k1,
                                             unsigned c0, unsigned c1,
                                             unsigned& o0, unsigned& o1) {
  unsigned ks2 = k0 ^ k1 ^ 0x1BD11BDAu;
  unsigned x0 = c0 + k0;
  unsigned x1 = c1 + k1;
#define TF_R(r) { x0 += x1; x1 = rotl32(x1, r); x1 ^= x0; }
  TF_R(13) TF_R(15) TF_R(26) TF_R(6)
  x0 += k1;  x1 += ks2 + 1u;
  TF_R(17) TF_R(29) TF_R(16) TF_R(24)
  x0 += ks2; x1 += k0 + 2u;
  TF_R(13) TF_R(15) TF_R(26) TF_R(6)
  x0 += k0;  x1 += k1 + 3u;
  TF_R(17) TF_R(29) TF_R(16) TF_R(24)
  x0 += k1;  x1 += ks2 + 4u;
  TF_R(13) TF_R(15) TF_R(26) TF_R(6)
  x0 += ks2; x1 += k0 + 5u;
#undef TF_R
  o0 = x0; o1 = x1;
}

// exact JAX partitionable gumbel for step key (kt0,kt1), flat index f
__device__ __forceinline__ double jax_gumbel(unsigned kt0, unsigned kt1,
                                             unsigned f) {
  unsigned r0, r1;
  threefry2x32(kt0, kt1, 0u, f, r0, r1);
  unsigned bits = r0 ^ r1;
  float uf = __uint_as_float((bits >> 9) | 0x3f800000u) - 1.0f;
  if (uf <= 0.f) uf = 1.17549435e-38f;  // np.finfo(float32).tiny
  return -log(-log((double)uf));
}

// ---- cross-block traffic: system-scope (sc0 sc1) — PROVEN semantics.
// (r1/r4 measured: sc0-only = SE scope, NOT sufficient for 8-block groups.)
// Multi-load asm blocks use "=&v" early-clobber: plain "=v" let an output
// land on an address register of a later load in the block (r2 core dump).
__device__ __forceinline__ void st_d(double* p, double v) {
  asm volatile("global_store_dwordx2 %0, %1, off sc0 sc1"
               :: "v"(p), "v"(v) : "memory");
}
__device__ __forceinline__ d2_t ld_d2(const double* p) {
  d2_t r;
  asm volatile("global_load_dwordx4 %0, %1, off sc0 sc1\n\t"
               "s_waitcnt vmcnt(0)" : "=&v"(r) : "v"(p));
  return r;
}
__device__ __forceinline__ void ld8(const double* pl, int v, double* o) {
  const double* a0 = pl + v;
  const double* a1 = pl + 512 + v;
  const double* a2 = pl + 1024 + v;
  const double* a3 = pl + 1536 + v;
  double o0, o1, o2, o3, o4, o5, o6, o7;
  asm volatile(
    "global_load_dwordx2 %[r0], %[p0], off sc0 sc1\n\t"
    "global_load_dwordx2 %[r1], %[p0], off offset:2048 sc0 sc1\n\t"
    "global_load_dwordx2 %[r2], %[p1], off sc0 sc1\n\t"
    "global_load_dwordx2 %[r3], %[p1], off offset:2048 sc0 sc1\n\t"
    "global_load_dwordx2 %[r4], %[p2], off sc0 sc1\n\t"
    "global_load_dwordx2 %[r5], %[p2], off offset:2048 sc0 sc1\n\t"
    "global_load_dwordx2 %[r6], %[p3], off sc0 sc1\n\t"
    "global_load_dwordx2 %[r7], %[p3], off offset:2048 sc0 sc1\n\t"
    "s_waitcnt vmcnt(0)"
    : [r0]"=&v"(o0), [r1]"=&v"(o1), [r2]"=&v"(o2), [r3]"=&v"(o3),
      [r4]"=&v"(o4), [r5]"=&v"(o5), [r6]"=&v"(o6), [r7]"=&v"(o7)
    : [p0]"v"(a0), [p1]"v"(a1), [p2]"v"(a2), [p3]"v"(a3));
  o[0]=o0; o[1]=o1; o[2]=o2; o[3]=o3; o[4]=o4; o[5]=o5; o[6]=o6; o[7]=o7;
}
__device__ __forceinline__ unsigned ld_u(const unsigned* p) {
  unsigned r;
  asm volatile("global_load_dword %0, %1, off sc0 sc1\n\t"
               "s_waitcnt vmcnt(0)" : "=&v"(r) : "v"(p) : "memory");
  return r;
}

// ---- 8-way group barrier via monotonic arrival counter ----
// arrive: drain all outstanding system stores, then ONE device-scope
// atomicAdd (m20: device scope by default -> cross-XCD safe).
// wait: ONE lane polls ONE address (vs r0's 64 lanes x 1 line -> MALL
// contention). Data ordering: data stores are drained (vmcnt 0) before the
// arrive-atomic issues, so ctr>=target implies all peers' data is visible.
__device__ __forceinline__ void gar(unsigned* ctr) {
  asm volatile("s_waitcnt vmcnt(0)" ::: "memory");
  __syncthreads();
  if (threadIdx.x == 0) atomicAdd(ctr, 1u);
}
__device__ __forceinline__ void gwt(unsigned* ctr, unsigned target) {
  if (threadIdx.x == 0) {
    int guard = 0;
    while (ld_u(ctr) < target) {
      if (++guard > 5000000) break;  // safety: never hang the bench
    }
  }
  asm volatile("" ::: "memory");
  __syncthreads();
}

extern "C" __global__ __launch_bounds__(NTHR)
void wavernn_pipe(const float* __restrict__ cond, const float* __restrict__ h0,
                  const float* __restrict__ W_ih, const float* __restrict__ W_hh,
                  const float* __restrict__ b_ih, const float* __restrict__ b_hh,
                  const float* __restrict__ W_hid, const float* __restrict__ b_hid,
                  const float* __restrict__ W_out, const float* __restrict__ b_out,
                  const float* __restrict__ emb,
                  float* __restrict__ out, double* __restrict__ ws) {
  const int tid = threadIdx.x;
  const int blk = blockIdx.x;
  const int g = blk >> 3;   // batch element (group)
  const int j = blk & 7;    // slot; slot-major => weight slice j is XCD-local
  const int lane = tid & 63, wv = tid >> 6;

  unsigned* ctrH = ((unsigned*)ws) + (size_t)g * 64;       // h barriers
  unsigned* ctrP = ((unsigned*)ws) + (size_t)g * 64 + 32;  // PL barriers
  double* G   = ws + WS_DBL_BASE + (size_t)g * GRP_STRIDE;
  double* Hb0 = G;
  double* Hb1 = G + 512;
  double* PL  = G + 1024;   // 8 x 256 partial logits

  __shared__ __attribute__((aligned(32))) double s_x[Cn];
  __shared__ __attribute__((aligned(32))) double s_h[Gn];
  __shared__ __attribute__((aligned(32))) double s_hid[64];
  __shared__ double s_hn[64], s_in[64], s_z[64];
  __shared__ double s_part[4][64];
  __shared__ double s_gum[256];
  __shared__ float  s_cond[Cn];
  __shared__ double s_pv[4];
  __shared__ int    s_pi[4];

  // ---- init: H0 slice <- h0; x0 = cond[:,0,:] + emb[128] ----
  if (tid < 64) st_d(&Hb0[j * 64 + tid],
                     (double)h0[(size_t)g * Gn + j * 64 + tid]);
  if (tid < Cn) s_x[tid] = (double)cond[(size_t)g * Tn * Cn + tid]
                         + (double)emb[128 * Cn + tid];
  gar(ctrH); gwt(ctrH, 8u);
  ((d2_t*)s_h)[tid] = ld_d2(Hb0 + 2 * tid);   // s_h = h_0
  __syncthreads();

  for (int t = 0; t < Tn; ++t) {
    double* hnxt = (t & 1) ? Hb0 : Hb1;       // buffer for h_{t+1}

    // ===== WINDOW (overlaps in-flight PL_{t-1} round trip) =====
    // h-dots over s_h = h_t. H-sum kept separate from X-sum.
    double ha0 = 0., ha1 = 0., ha2 = 0., ha3 = 0.;
    if (wv <= 2) {
      const int row = wv * 512 + j * 64 + lane;   // r(0) z(1) hn(2) rows
      const float4* wh = (const float4*)(W_hh + (size_t)row * Gn);
      const double4* h4 = (const double4*)s_h;
#pragma unroll 8
      for (int k = 0; k < Gn / 4; ++k) {
        float4 w = wh[k]; double4 hv = h4[k];
        ha0 = fma((double)w.x, hv.x, ha0); ha1 = fma((double)w.y, hv.y, ha1);
        ha2 = fma((double)w.z, hv.z, ha2); ha3 = fma((double)w.w, hv.w, ha3);
      }
      if (wv == 2)
        s_hn[lane] = ((ha0 + ha1) + (ha2 + ha3)) + (double)b_hh[row];
    } else {
      // wave 3: stage cond[:,t,:] ; gumbel for step t-1 (consumed at resolve)
      const int c0 = 2 * lane;
      s_cond[c0]     = cond[((size_t)g * Tn + t) * Cn + c0];
      s_cond[c0 + 1] = cond[((size_t)g * Tn + t) * Cn + c0 + 1];
      if (t > 0) {
        unsigned kt0, kt1;
        threefry2x32(0u, 1u, 0u, (unsigned)(t - 1), kt0, kt1);
#pragma unroll
        for (int i = 0; i < 4; ++i) {
          int v = 4 * lane + i;
          s_gum[v] = jax_gumbel(kt0, kt1, (unsigned)(g * Vn + v));
        }
      }
    }

    // ===== PL wait + resolve of step t-1 =====
    if (t > 0) {
      gwt(ctrP, (unsigned)(8 * t));        // PL_{t-1} ready
      const int v = tid;
      double l[8];
      ld8(PL, v, l);
      double logit = ((((((((l[0] + l[1]) + l[2]) + l[3]) + l[4]) + l[5])
                       + l[6]) + l[7])) + (double)b_out[v];
      if (j == 0)
        out[(size_t)g * Tn * Vn + (size_t)(t - 1) * Vn + v] = (float)logit;
      double bv = logit + s_gum[v];
      int bi = v;
#pragma unroll
      for (int off = 1; off < 64; off <<= 1) {
        double ov = __shfl_xor(bv, off, 64);
        int oi = __shfl_xor(bi, off, 64);
        if (ov > bv || (ov == bv && oi < bi)) { bv = ov; bi = oi; }
      }
      if (lane == 0) { s_pv[wv] = bv; s_pi[wv] = bi; }
      __syncthreads();
      double fv = s_pv[0]; int fi = s_pi[0];
#pragma unroll
      for (int w = 1; w < 4; ++w) {
        double ov = s_pv[w]; int oi = s_pi[w];
        if (ov > fv || (ov == fv && oi < fi)) { fv = ov; fi = oi; }
      }
      const int samp = fi;
      if (tid == 0 && j == 0)
        out[OUT_SAMP + (size_t)g * Tn + (t - 1)] = (float)samp;
      if (tid < Cn)
        s_x[tid] = (double)s_cond[tid] + (double)emb[(size_t)samp * Cn + tid];
      __syncthreads();
    } else {
      __syncthreads();  // order window LDS writes vs x-phase reads
    }

    // ===== x-phase: x-dots + sigmoids =====
    double r_reg = 0.;
    if (wv <= 1) {
      const int row = wv * 512 + j * 64 + lane;
      const float4* wi = (const float4*)(W_ih + (size_t)row * Cn);
      const double4* x4 = (const double4*)s_x;
      double xa0 = 0., xa1 = 0., xa2 = 0., xa3 = 0.;
#pragma unroll 8
      for (int k = 0; k < Cn / 4; ++k) {
        float4 w = wi[k]; double4 xv = x4[k];
        xa0 = fma((double)w.x, xv.x, xa0); xa1 = fma((double)w.y, xv.y, xa1);
        xa2 = fma((double)w.z, xv.z, xa2); xa3 = fma((double)w.w, xv.w, xa3);
      }
      double gi = ((xa0 + xa1) + (xa2 + xa3)) + (double)b_ih[row];
      double gh = ((ha0 + ha1) + (ha2 + ha3)) + (double)b_hh[row];
      double pre = gi + gh;
      double sig = 1.0 / (1.0 + exp(-pre));
      if (wv == 0) r_reg = sig; else s_z[lane] = sig;
    } else if (wv == 3) {
      const int row = 1024 + j * 64 + lane;
      const float4* wi = (const float4*)(W_ih + (size_t)row * Cn);
      const double4* x4 = (const double4*)s_x;
      double a0 = 0., a1 = 0., a2 = 0., a3 = 0.;
#pragma unroll 8
      for (int k = 0; k < Cn / 4; ++k) {
        float4 w = wi[k]; double4 xv = x4[k];
        a0 = fma((double)w.x, xv.x, a0); a1 = fma((double)w.y, xv.y, a1);
        a2 = fma((double)w.z, xv.z, a2); a3 = fma((double)w.w, xv.w, a3);
      }
      s_in[lane] = ((a0 + a1) + (a2 + a3)) + (double)b_ih[row];
    }
    __syncthreads();

    // ===== combine (wave 0) -> h_{t+1} slice =====
    if (wv == 0) {
      double z = s_z[lane];
      double n = tanh(s_in[lane] + r_reg * s_hn[lane]);
      double hv = (1.0 - z) * n + z * s_h[j * 64 + lane];
      st_d(&hnxt[j * 64 + lane], hv);
    }
    gar(ctrH);
    gwt(ctrH, (unsigned)(8 * (t + 2)));
    ((d2_t*)s_h)[tid] = ld_d2(hnxt + 2 * tid);   // s_h = h_{t+1}
    __syncthreads();
    if (t == Tn - 1 && j == 0) {
      out[OUT_HF + (size_t)g * Gn + tid] = (float)s_h[tid];
      out[OUT_HF + (size_t)g * Gn + tid + 256] = (float)s_h[tid + 256];
    }

    // ===== B: hid slice + partial logits =====
    {
      const int row = j * 64 + lane;          // q = wv (wave-uniform)
      const float4* wr = (const float4*)(W_hid + (size_t)row * Gn + wv * 128);
      const double4* hh = (const double4*)(s_h + wv * 128);
      double a0 = 0., a1 = 0., a2 = 0., a3 = 0.;
#pragma unroll 8
      for (int k = 0; k < 32; ++k) {
        float4 w = wr[k]; double4 hv = hh[k];
        a0 = fma((double)w.x, hv.x, a0); a1 = fma((double)w.y, hv.y, a1);
        a2 = fma((double)w.z, hv.z, a2); a3 = fma((double)w.w, hv.w, a3);
      }
      s_part[wv][lane] = (a0 + a1) + (a2 + a3);
    }
    __syncthreads();
    if (tid < 64) {
      double acc = (s_part[0][tid] + s_part[1][tid])
                 + (s_part[2][tid] + s_part[3][tid])
                 + (double)b_hid[j * 64 + tid];
      s_hid[tid] = acc > 0.0 ? acc : 0.0;
    }
    __syncthreads();
    {
      const int v = tid;
      const float4* wr = (const float4*)(W_out + (size_t)v * Hn + j * 64);
      const double4* hh = (const double4*)s_hid;
      double a0 = 0., a1 = 0., a2 = 0., a3 = 0.;
#pragma unroll 8
      for (int k = 0; k < 16; ++k) {
        float4 w = wr[k]; double4 hv = hh[k];
        a0 = fma((double)w.x, hv.x, a0); a1 = fma((double)w.y, hv.y, a1);
        a2 = fma((double)w.z, hv.z, a2); a3 = fma((double)w.w, hv.w, a3);
      }
      st_d(&PL[j * 256 + v], (a0 + a1) + (a2 + a3));
    }
    gar(ctrP);
  }

  // ===== final resolve: step Tn-1 =====
  gwt(ctrP, (unsigned)(8 * Tn));
  {
    const int v = tid;
    double l[8];
    ld8(PL, v, l);
    double logit = ((((((((l[0] + l[1]) + l[2]) + l[3]) + l[4]) + l[5])
                     + l[6]) + l[7])) + (double)b_out[v];
    if (j == 0)
      out[(size_t)g * Tn * Vn + (size_t)(Tn - 1) * Vn + v] = (float)logit;
    unsigned kt0, kt1;
    threefry2x32(0u, 1u, 0u, (unsigned)(Tn - 1), kt0, kt1);
    double gum = jax_gumbel(kt0, kt1, (unsigned)(g * Vn + v));
    double bv = logit + gum;
    int bi = v;
#pragma unroll
    for (int off = 1; off < 64; off <<= 1) {
      double ov = __shfl_xor(bv, off, 64);
      int oi = __shfl_xor(bi, off, 64);
      if (ov > bv || (ov == bv && oi < bi)) { bv = ov; bi = oi; }
    }
    if (lane == 0) { s_pv[wv] = bv; s_pi[wv] = bi; }
    __syncthreads();
    double fv = s_pv[0]; int fi = s_pi[0];
#pragma unroll
    for (int w = 1; w < 4; ++w) {
      double ov = s_pv[w]; int oi = s_pi[w];
      if (ov > fv || (ov == fv && oi < fi)) { fv = ov; fi = oi; }
    }
    if (tid == 0 && j == 0)
      out[OUT_SAMP + (size_t)g * Tn + (Tn - 1)] = (float)fi;
  }
}

extern "C" void kernel_launch(void* const* d_in, const int* in_sizes, int n_in,
                              void* d_out, int out_size, void* d_ws, size_t ws_size,
                              hipStream_t stream) {
  const float* cond  = (const float*)d_in[0];
  const float* h0    = (const float*)d_in[1];
  const float* W_ih  = (const float*)d_in[2];
  const float* W_hh  = (const float*)d_in[3];
  const float* b_ih  = (const float*)d_in[4];
  const float* b_hh  = (const float*)d_in[5];
  const float* W_hid = (const float*)d_in[6];
  const float* b_hid = (const float*)d_in[7];
  const float* W_out = (const float*)d_in[8];
  const float* b_out = (const float*)d_in[9];
  const float* emb   = (const float*)d_in[10];

  // zero the counter region (ws is poisoned 0xAA before every call)
  hipMemsetAsync(d_ws, 0, 4096, stream);
  hipLaunchKernelGGL(wavernn_pipe, dim3(NBLK), dim3(NTHR), 0, stream,
                     cond, h0, W_ih, W_hh, b_ih, b_hh, W_hid, b_hid,
                     W_out, b_out, emb, (float*)d_out, (double*)d_ws);
}